// Round 5
// baseline (412.690 us; speedup 1.0000x reference)
//
#include <hip/hip_runtime.h>

#define EPSF 1e-5f
#define TOTBINS 1146880   // 70*16*1024

typedef _Float16 v8h __attribute__((ext_vector_type(8)));
typedef float v4f __attribute__((ext_vector_type(4)));

// ---- workspace offsets (in float slots) ----
#define OFF_PARTX   1146880
#define OFF_W1F     1149952
#define OFF_B1F     1150144
#define OFF_PMU1    1150208
#define OFF_M1N     1166592
#define OFF_MU1     1170688
#define OFF_W2F     1170752
#define OFF_B2F     1178944
#define OFF_PMU2    1179072
#define OFF_M2N     1211840
#define OFF_MU2     1228224
#define OFF_W3H     1228352   // 1024x128 f16 = 65536 slots
#define OFF_W3L     1293888
#define OFF_B3F     1359424
#define OFF_H1      1360448   // 16*64*4096 f32; reused as partM2 after layer2
#define OFF_H2H     5554752   // 16*4096*128 f16; reused as partM1 before layer2
#define OFF_H2L     9749056   // ends 13943360 (55.8 MB)

// ---------- stats of x ----------
__global__ void k_statsX(const float* __restrict__ x, float* __restrict__ part){
  __shared__ float red[12][256];
  int t = threadIdx.x;
  int s = blockIdx.x*256 + t;
  int b = s >> 12, n = s & 4095;
  const float* xb = x + (size_t)b*12288 + n;
  float x0 = xb[0], x1 = xb[4096], x2 = xb[8192];
  float v[12] = {x0,x1,x2, x0*x0,x0*x1,x0*x2, x1*x1,x1*x2,x2*x2, 0.f,0.f,0.f};
  #pragma unroll
  for(int j=0;j<12;j++) red[j][t]=v[j];
  __syncthreads();
  for(int off=128; off>0; off>>=1){
    if(t<off){
      #pragma unroll
      for(int j=0;j<12;j++) red[j][t]+=red[j][t+off];
    }
    __syncthreads();
  }
  if(t<12) part[blockIdx.x*12+t]=red[t][0];
}

__global__ void k_fold1(const float* __restrict__ part,
                        const float* __restrict__ w1, const float* __restrict__ b1,
                        const float* __restrict__ g1, const float* __restrict__ be1,
                        float* __restrict__ W1f, float* __restrict__ B1f){
  __shared__ double S[12];
  int t=threadIdx.x;
  if(t<12){
    double a=0.0;
    for(int s=0;s<256;s++) a+=(double)part[s*12+t];
    S[t]=a;
  }
  __syncthreads();
  if(t<64){
    double inv = 1.0/65536.0;
    double mu[3]={S[0]*inv,S[1]*inv,S[2]*inv};
    double M[3][3];
    M[0][0]=S[3]*inv; M[0][1]=S[4]*inv; M[0][2]=S[5]*inv;
    M[1][1]=S[6]*inv; M[1][2]=S[7]*inv; M[2][2]=S[8]*inv;
    M[1][0]=M[0][1]; M[2][0]=M[0][2]; M[2][1]=M[1][2];
    double w[3]={(double)w1[t*3],(double)w1[t*3+1],(double)w1[t*3+2]};
    double wm=0.0, q=0.0;
    for(int c=0;c<3;c++){
      wm += w[c]*mu[c];
      for(int d=0;d<3;d++) q += w[c]*w[d]*M[c][d];
    }
    double var = q - wm*wm;
    double m = wm + (double)b1[t];
    double sc = (double)g1[t] / sqrt(var + (double)EPSF);
    for(int c=0;c<3;c++) W1f[t*3+c]=(float)(w[c]*sc);
    B1f[t]=(float)(((double)b1[t]-m)*sc + (double)be1[t]);
  }
}

__global__ void k_layer1(const float* __restrict__ x, const float* __restrict__ W1f,
                         const float* __restrict__ B1f, float* __restrict__ h1){
  int s = blockIdx.x*256 + threadIdx.x;
  int b = s>>12, n = s&4095;
  const float* xb = x + (size_t)b*12288 + n;
  float x0=xb[0], x1=xb[4096], x2=xb[8192];
  float* hb = h1 + (size_t)b*262144 + n;
  for(int f=0; f<64; f++){
    float v = fmaf(W1f[f*3+2],x2, fmaf(W1f[f*3+1],x1, fmaf(W1f[f*3],x0, B1f[f])));
    hb[(size_t)f*4096] = v>0.f ? v : 0.f;
  }
}

__global__ void k_stats1(const float* __restrict__ h1, float* __restrict__ partM,
                         float* __restrict__ partMu){
  __shared__ float tile[64][129];
  int t=threadIdx.x, wg=blockIdx.x;
  int s0=wg*256;
  int b=s0>>12, n0=s0&4095;
  int ti=t&15, tj=t>>4;
  int i0=ti*4, j0=tj*4;
  float acc[4][4];
  #pragma unroll
  for(int i=0;i<4;i++){
    #pragma unroll
    for(int j=0;j<4;j++) acc[i][j]=0.f;
  }
  float mu=0.f;
  for(int half=0; half<2; half++){
    int nb=n0+half*128;
    __syncthreads();
    {
      int col=t&127, cr=t>>7;
      for(int p=0;p<32;p++){
        int c=cr+2*p;
        tile[c][col]=h1[((size_t)b*64+c)*4096 + nb + col];
      }
    }
    __syncthreads();
    for(int k=0;k<128;k++){
      float a[4], c4[4];
      #pragma unroll
      for(int i=0;i<4;i++) a[i]=tile[i0+i][k];
      #pragma unroll
      for(int j=0;j<4;j++) c4[j]=tile[j0+j][k];
      #pragma unroll
      for(int i=0;i<4;i++){
        #pragma unroll
        for(int j=0;j<4;j++) acc[i][j]=fmaf(a[i],c4[j],acc[i][j]);
      }
    }
    if(t<64){
      float s=0.f;
      for(int k=0;k<128;k++) s+=tile[t][k];
      mu+=s;
    }
  }
  #pragma unroll
  for(int i=0;i<4;i++){
    #pragma unroll
    for(int j=0;j<4;j++)
      partM[(size_t)wg*4096+(i0+i)*64+(j0+j)]=acc[i][j];
  }
  if(t<64) partMu[wg*64+t]=mu;
}

__global__ void k_reduceM1(const float* __restrict__ partM, const float* __restrict__ partMu,
                           float* __restrict__ M1n, float* __restrict__ mu1){
  int e=blockIdx.x*256+threadIdx.x;
  double a=0.0;
  for(int s=0;s<256;s++) a+=(double)partM[(size_t)s*4096+e];
  M1n[e]=(float)(a/65536.0);
  if(e<64){
    double m=0.0;
    for(int s=0;s<256;s++) m+=(double)partMu[s*64+e];
    mu1[e]=(float)(m/65536.0);
  }
}

__global__ void k_fold2(const float* __restrict__ w2, const float* __restrict__ b2,
                        const float* __restrict__ g2, const float* __restrict__ be2,
                        const float* __restrict__ M1n, const float* __restrict__ mu1,
                        float* __restrict__ W2f, float* __restrict__ B2f){
  int f=blockIdx.x, t=threadIdx.x;
  __shared__ float w[64];
  w[t]=w2[f*64+t];
  __syncthreads();
  double tm=0.0;
  for(int c=0;c<64;c++) tm += (double)w[c]*(double)M1n[c*64+t];
  double pv=tm*(double)w[t];
  double pm=(double)w[t]*(double)mu1[t];
  #pragma unroll
  for(int off=32;off>0;off>>=1){
    pv+=__shfl_xor(pv,off,64);
    pm+=__shfl_xor(pm,off,64);
  }
  double var=pv-pm*pm;
  double m=pm+(double)b2[f];
  double sc=(double)g2[f]/sqrt(var+(double)EPSF);
  W2f[f*64+t]=(float)((double)w[t]*sc);
  if(t==0) B2f[f]=(float)(((double)b2[f]-m)*sc+(double)be2[f]);
}

// ---------- layer2 GEMM: writes transposed f16 hi/lo planes [b][n][c] ----------
__global__ __launch_bounds__(256) void k_layer2(
    const float* __restrict__ h1, const float* __restrict__ W2f,
    const float* __restrict__ B2f, _Float16* __restrict__ h2h,
    _Float16* __restrict__ h2l){
  __shared__ __align__(16) float la[32][68];
  __shared__ __align__(16) float lb[32][256];
  int t=threadIdx.x, wg=blockIdx.x;
  int b=wg>>5;
  int r=wg&31;
  int f0=(r>>4)<<6;
  int n0=(r&15)<<8;
  int fx=t&7, nx=t>>3;
  int cl=t&31, flb=t>>5;
  int n4=(t&63)<<2, cb=t>>6;
  float acc[8][8];
  #pragma unroll
  for(int i=0;i<8;i++){
    #pragma unroll
    for(int j=0;j<8;j++) acc[i][j]=0.f;
  }
  for(int kc=0;kc<2;kc++){
    int k0=kc*32;
    __syncthreads();
    #pragma unroll
    for(int p=0;p<8;p++){
      int fl=flb+8*p;
      la[cl][fl]=W2f[(size_t)(f0+fl)*64+k0+cl];
    }
    #pragma unroll
    for(int p=0;p<8;p++){
      int c=cb+4*p;
      *(float4*)&lb[c][n4]=*(const float4*)(h1+((size_t)((b<<6)+k0+c)<<12)+n0+n4);
    }
    __syncthreads();
    #pragma unroll 8
    for(int k=0;k<32;k++){
      float a[8],bb[8];
      #pragma unroll
      for(int i=0;i<8;i++) a[i]=la[k][fx*8+i];
      #pragma unroll
      for(int j=0;j<8;j++) bb[j]=lb[k][nx*8+j];
      #pragma unroll
      for(int i=0;i<8;i++){
        #pragma unroll
        for(int j=0;j<8;j++) acc[i][j]=fmaf(a[i],bb[j],acc[i][j]);
      }
    }
  }
  float bv[8];
  #pragma unroll
  for(int i=0;i<8;i++) bv[i]=B2f[f0+fx*8+i];
  #pragma unroll
  for(int j=0;j<8;j++){
    int n=n0+nx*8+j;
    v8h vh, vl;
    #pragma unroll
    for(int i=0;i<8;i++){
      float v=acc[i][j]+bv[i];
      v = v>0.f ? v : 0.f;
      _Float16 hh=(_Float16)v;
      vh[i]=hh;
      vl[i]=(_Float16)(v-(float)hh);
    }
    size_t off=((size_t)((b<<12)+n))*128 + f0 + fx*8;
    *(v8h*)(h2h+off)=vh;
    *(v8h*)(h2l+off)=vl;
  }
}

// ---------- stats of h2 from f16 planes ----------
__global__ void k_stats2(const _Float16* __restrict__ h2h, const _Float16* __restrict__ h2l,
                         float* __restrict__ partM, float* __restrict__ partMu){
  __shared__ __align__(16) float tl[64][132];
  int t=threadIdx.x, wg=blockIdx.x;
  int s0=wg*256;
  int b=s0>>12, n0=s0&4095;
  int ti=t&15, tj=t>>4;
  float acc[8][8];
  #pragma unroll
  for(int i=0;i<8;i++){
    #pragma unroll
    for(int j=0;j<8;j++) acc[i][j]=0.f;
  }
  float mu=0.f;
  for(int tile=0; tile<4; tile++){
    int nb=n0+tile*64;
    __syncthreads();
    {
      int nr=t>>2, cq=(t&3)<<5;
      const _Float16* ph = h2h + ((size_t)((b<<12)+nb+nr))*128 + cq;
      const _Float16* pl = h2l + ((size_t)((b<<12)+nb+nr))*128 + cq;
      #pragma unroll
      for(int q=0;q<4;q++){
        v8h hh=*(const v8h*)(ph+q*8);
        v8h ll=*(const v8h*)(pl+q*8);
        float4 v0=make_float4((float)hh[0]+(float)ll[0],(float)hh[1]+(float)ll[1],
                              (float)hh[2]+(float)ll[2],(float)hh[3]+(float)ll[3]);
        float4 v1=make_float4((float)hh[4]+(float)ll[4],(float)hh[5]+(float)ll[5],
                              (float)hh[6]+(float)ll[6],(float)hh[7]+(float)ll[7]);
        *(float4*)&tl[nr][cq+q*8]   = v0;
        *(float4*)&tl[nr][cq+q*8+4] = v1;
      }
    }
    __syncthreads();
    for(int k=0;k<64;k++){
      float a[8],bb[8];
      #pragma unroll
      for(int i=0;i<8;i++) a[i]=tl[k][i*16+ti];
      #pragma unroll
      for(int j=0;j<8;j++) bb[j]=tl[k][j*16+tj];
      #pragma unroll
      for(int i=0;i<8;i++){
        #pragma unroll
        for(int j=0;j<8;j++) acc[i][j]=fmaf(a[i],bb[j],acc[i][j]);
      }
    }
    if(t<128){
      float s=0.f;
      for(int k=0;k<64;k++) s+=tl[k][t];
      mu+=s;
    }
  }
  #pragma unroll
  for(int i=0;i<8;i++){
    #pragma unroll
    for(int j=0;j<8;j++)
      partM[(size_t)wg*16384+(i*16+ti)*128+(j*16+tj)]=acc[i][j];
  }
  if(t<128) partMu[wg*128+t]=mu;
}

__global__ void k_reduceM2(const float* __restrict__ partM, const float* __restrict__ partMu,
                           float* __restrict__ M2n, float* __restrict__ mu2){
  int e=blockIdx.x*256+threadIdx.x;
  double a=0.0;
  for(int s=0;s<256;s++) a+=(double)partM[(size_t)s*16384+e];
  M2n[e]=(float)(a/65536.0);
  if(e<128){
    double m=0.0;
    for(int s=0;s<256;s++) m+=(double)partMu[s*128+e];
    mu2[e]=(float)(m/65536.0);
  }
}

// ---------- fold layer3: produce f16 hi/lo weight planes ----------
__global__ void k_fold3(const float* __restrict__ w3, const float* __restrict__ b3,
                        const float* __restrict__ g3, const float* __restrict__ be3,
                        const float* __restrict__ M2n, const float* __restrict__ mu2,
                        _Float16* __restrict__ w3h, _Float16* __restrict__ w3l,
                        float* __restrict__ B3f){
  int f=blockIdx.x, t=threadIdx.x;
  __shared__ float w[128];
  __shared__ double rv[2], rm[2];
  w[t]=w3[f*128+t];
  __syncthreads();
  double tm=0.0;
  for(int c=0;c<128;c++) tm += (double)w[c]*(double)M2n[c*128+t];
  double pv=tm*(double)w[t];
  double pm=(double)w[t]*(double)mu2[t];
  #pragma unroll
  for(int off=32;off>0;off>>=1){
    pv+=__shfl_xor(pv,off,64);
    pm+=__shfl_xor(pm,off,64);
  }
  if((t&63)==0){ rv[t>>6]=pv; rm[t>>6]=pm; }
  __syncthreads();
  double pmt=rm[0]+rm[1];
  double var=(rv[0]+rv[1]) - pmt*pmt;
  double m=pmt + (double)b3[f];
  double sc=(double)g3[f]/sqrt(var+(double)EPSF);
  float Wf=(float)((double)w[t]*sc);
  _Float16 hh=(_Float16)Wf;
  w3h[f*128+t]=hh;
  w3l[f*128+t]=(_Float16)(Wf-(float)hh);
  if(t==0) B3f[f]=(float)(((double)b3[f]-m)*sc+(double)be3[f]);
}

// ---------- layer3 MFMA GEMM fused with histogram: LDS-free B loads ----------
// grid 1024 = 16b x 16 ftile(64f) x 4 nslice(1024n); 4 waves, wave wv = 16 f rows.
// B fragments loaded global->VGPR directly (h2 layout is fragment-contiguous);
// no barriers in the main loop. LDS = parity-split u32 histogram only.
__global__ __launch_bounds__(256,4) void k_gemm3_hist(
    const _Float16* __restrict__ h2h, const _Float16* __restrict__ h2l,
    const _Float16* __restrict__ w3h, const _Float16* __restrict__ w3l,
    const float* __restrict__ B3f, unsigned int* __restrict__ hist){
  __shared__ unsigned int lh[8960];   // 2 parity copies x 64ch x 70 bins, u32
  int t=threadIdx.x, wg=blockIdx.x;
  int wv=t>>6, l=t&63;
  int lrow=l&15, lgrp=l>>4;
  int b=wg>>6;
  int r=wg&63;
  int f0=(r>>2)<<6;
  int sl=r&3;
  int base=70*((b<<10)+f0);
  for(int i=t;i<8960;i+=256) lh[i]=0u;
  __syncthreads();

  // resident A fragments: f = f0 + wv*16 + lrow, k = s*32 + lgrp*8 + e
  v8h Ah[4], Al[4];
  {
    const _Float16* ph = w3h + (size_t)(f0 + wv*16 + lrow)*128 + lgrp*8;
    const _Float16* pl = w3l + (size_t)(f0 + wv*16 + lrow)*128 + lgrp*8;
    #pragma unroll
    for(int s=0;s<4;s++){
      Ah[s]=*(const v8h*)(ph+s*32);
      Al[s]=*(const v8h*)(pl+s*32);
    }
  }
  float bias[4]; int base70[4];
  #pragma unroll
  for(int rr=0;rr<4;rr++){
    int fl_=wv*16+lgrp*4+rr;
    bias[rr]=B3f[f0+fl_];
    base70[rr]=fl_*70;
  }
  const float wbin=(10.0f-(-10.0f))/70.0f;
  const float inv_w=1.0f/wbin;
  const float off_w=10.0f*inv_w;
  unsigned int* lhp = lh + (lrow&1)*4480;

  // B fragment source: n = sl*1024 + nt*16 + lrow, k = s*32 + lgrp*8 + e
  const _Float16* pH = h2h + ((size_t)((b<<12)+sl*1024+lrow))*128 + lgrp*8;
  const _Float16* pL = h2l + ((size_t)((b<<12)+sl*1024+lrow))*128 + lgrp*8;

  #pragma unroll 2
  for(int nt=0;nt<64;nt++){
    v8h Bh[4],Bl[4];
    #pragma unroll
    for(int s=0;s<4;s++){
      Bh[s]=*(const v8h*)(pH+s*32);
      Bl[s]=*(const v8h*)(pL+s*32);
    }
    pH += 2048; pL += 2048;
    v4f acc={bias[0],bias[1],bias[2],bias[3]};
    #pragma unroll
    for(int s=0;s<4;s++){
      acc=__builtin_amdgcn_mfma_f32_16x16x32_f16(Ah[s],Bh[s],acc,0,0,0);
      acc=__builtin_amdgcn_mfma_f32_16x16x32_f16(Ah[s],Bl[s],acc,0,0,0);
      acc=__builtin_amdgcn_mfma_f32_16x16x32_f16(Al[s],Bh[s],acc,0,0,0);
    }
    // epilogue: C layout col=l&15 (n), row=lgrp*4+rr (f); bin and count
    #pragma unroll
    for(int rr=0;rr<4;rr++){
      float q=fmaf(acc[rr],inv_w,off_w);
      if(q>-2.0e9f && q<2.0e9f){
        int bin=(int)floorf(q);
        int loc=base70[rr]+bin;
        if((unsigned)loc<4480u){
          atomicAdd(&lhp[loc],1u);
        }else{
          int g=base+loc;
          if(g>=0 && g<TOTBINS) atomicAdd(&hist[g],1u);
        }
      }
    }
  }
  __syncthreads();
  for(int i=t;i<4480;i+=256){
    unsigned int c=lh[i]+lh[i+4480];
    if(c) atomicAdd(&hist[base+i],c);
  }
}

__global__ void k_argmax(const unsigned int* __restrict__ hist, float* __restrict__ out){
  int g = blockIdx.x*256 + threadIdx.x;
  const unsigned int* h = hist + (size_t)g*70;
  unsigned int best=h[0]; int arg=0;
  for(int k=1;k<70;k++){
    unsigned int c=h[k];
    if(c>best){ best=c; arg=k; }
  }
  out[g]=(float)arg;
}

extern "C" void kernel_launch(void* const* d_in, const int* in_sizes, int n_in,
                              void* d_out, int out_size, void* d_ws, size_t ws_size,
                              hipStream_t stream){
  const float* x  =(const float*)d_in[0];
  const float* w1 =(const float*)d_in[1];
  const float* b1 =(const float*)d_in[2];
  const float* g1 =(const float*)d_in[3];
  const float* be1=(const float*)d_in[4];
  const float* w2 =(const float*)d_in[5];
  const float* b2 =(const float*)d_in[6];
  const float* g2 =(const float*)d_in[7];
  const float* be2=(const float*)d_in[8];
  const float* w3 =(const float*)d_in[9];
  const float* b3 =(const float*)d_in[10];
  const float* g3 =(const float*)d_in[11];
  const float* be3=(const float*)d_in[12];

  float* ws=(float*)d_ws;
  unsigned int* hist=(unsigned int*)ws;
  float* partX = ws+OFF_PARTX;
  float* W1f   = ws+OFF_W1F;
  float* B1f   = ws+OFF_B1F;
  float* pMu1  = ws+OFF_PMU1;
  float* M1n   = ws+OFF_M1N;
  float* mu1   = ws+OFF_MU1;
  float* W2f   = ws+OFF_W2F;
  float* B2f   = ws+OFF_B2F;
  float* pMu2  = ws+OFF_PMU2;
  float* M2n   = ws+OFF_M2N;
  float* mu2   = ws+OFF_MU2;
  _Float16* w3h=(_Float16*)(ws+OFF_W3H);
  _Float16* w3l=(_Float16*)(ws+OFF_W3L);
  float* B3f   = ws+OFF_B3F;
  float* h1    = ws+OFF_H1;
  _Float16* h2h=(_Float16*)(ws+OFF_H2H);
  _Float16* h2l=(_Float16*)(ws+OFF_H2L);
  float* partM1=(float*)(ws+OFF_H2H);   // free until k_layer2
  float* partM2=(float*)(ws+OFF_H1);    // h1 free after k_layer2

  hipMemsetAsync(hist, 0, (size_t)TOTBINS*sizeof(unsigned int), stream);

  k_statsX  <<<256,256,0,stream>>>(x, partX);
  k_fold1   <<<1,  256,0,stream>>>(partX,w1,b1,g1,be1,W1f,B1f);
  k_layer1  <<<256,256,0,stream>>>(x,W1f,B1f,h1);
  k_stats1  <<<256,256,0,stream>>>(h1,partM1,pMu1);
  k_reduceM1<<<16, 256,0,stream>>>(partM1,pMu1,M1n,mu1);
  k_fold2   <<<128, 64,0,stream>>>(w2,b2,g2,be2,M1n,mu1,W2f,B2f);
  k_layer2  <<<512,256,0,stream>>>(h1,W2f,B2f,h2h,h2l);
  k_stats2  <<<256,256,0,stream>>>(h2h,h2l,partM2,pMu2);
  k_reduceM2<<<64, 256,0,stream>>>(partM2,pMu2,M2n,mu2);
  k_fold3   <<<1024,128,0,stream>>>(w3,b3,g3,be3,M2n,mu2,w3h,w3l,B3f);
  k_gemm3_hist<<<1024,256,0,stream>>>(h2h,h2l,w3h,w3l,B3f,hist);
  k_argmax  <<<64, 256,0,stream>>>(hist,(float*)d_out);
}

// Round 7
// 262.395 us; speedup vs baseline: 1.5728x; 1.5728x over previous
//
#include <hip/hip_runtime.h>

#define EPSF 1e-5f
#define TOTBINS 1146880   // 70*16*1024

typedef _Float16 v8h __attribute__((ext_vector_type(8)));
typedef _Float16 v4h __attribute__((ext_vector_type(4)));
typedef float v4f __attribute__((ext_vector_type(4)));

// ---- workspace offsets (in float slots) ----
#define OFF_PARTX   1146880
#define OFF_W1F     1149952
#define OFF_B1F     1150144
#define OFF_PMU1    1150208
#define OFF_M1N     1166592
#define OFF_MU1     1170688
#define OFF_W2H     1170752   // 128x64 f16 = 8192 halves = 4096 float slots
#define OFF_W2L     1174848
#define OFF_B2F     1178944
#define OFF_PMU2    1179072
#define OFF_M2N     1211840
#define OFF_MU2     1228224
#define OFF_W3H     1228352   // 1024x128 f16 = 131072 halves = 65536 float slots
#define OFF_W3L     1293888
#define OFF_B3F     1359424
#define OFF_H1H     1360448   // 16*4096*64 f16 = 2097152 float slots
#define OFF_H1L     3457600   // (h1h..h1l region reused as partM2 after layer2)
#define OFF_H2H     5554752   // 16*4096*128 f16 = 4194304 float slots; reused as partM1 early
#define OFF_H2L     9749056   // ends 13943360 (55.8 MB)

#define GLL(src,dst) __builtin_amdgcn_global_load_lds( \
    (const __attribute__((address_space(1))) void*)(src), \
    (__attribute__((address_space(3))) void*)(dst), 16, 0, 0)

// ---------- stats of x ----------
__global__ void k_statsX(const float* __restrict__ x, float* __restrict__ part){
  __shared__ float red[12][256];
  int t = threadIdx.x;
  int s = blockIdx.x*256 + t;
  int b = s >> 12, n = s & 4095;
  const float* xb = x + (size_t)b*12288 + n;
  float x0 = xb[0], x1 = xb[4096], x2 = xb[8192];
  float v[12] = {x0,x1,x2, x0*x0,x0*x1,x0*x2, x1*x1,x1*x2,x2*x2, 0.f,0.f,0.f};
  #pragma unroll
  for(int j=0;j<12;j++) red[j][t]=v[j];
  __syncthreads();
  for(int off=128; off>0; off>>=1){
    if(t<off){
      #pragma unroll
      for(int j=0;j<12;j++) red[j][t]+=red[j][t+off];
    }
    __syncthreads();
  }
  if(t<12) part[blockIdx.x*12+t]=red[t][0];
}

__global__ void k_fold1(const float* __restrict__ part,
                        const float* __restrict__ w1, const float* __restrict__ b1,
                        const float* __restrict__ g1, const float* __restrict__ be1,
                        float* __restrict__ W1f, float* __restrict__ B1f){
  __shared__ double S[12];
  int t=threadIdx.x;
  if(t<12){
    double a=0.0;
    for(int s=0;s<256;s++) a+=(double)part[s*12+t];
    S[t]=a;
  }
  __syncthreads();
  if(t<64){
    double inv = 1.0/65536.0;
    double mu[3]={S[0]*inv,S[1]*inv,S[2]*inv};
    double M[3][3];
    M[0][0]=S[3]*inv; M[0][1]=S[4]*inv; M[0][2]=S[5]*inv;
    M[1][1]=S[6]*inv; M[1][2]=S[7]*inv; M[2][2]=S[8]*inv;
    M[1][0]=M[0][1]; M[2][0]=M[0][2]; M[2][1]=M[1][2];
    double w[3]={(double)w1[t*3],(double)w1[t*3+1],(double)w1[t*3+2]};
    double wm=0.0, q=0.0;
    for(int c=0;c<3;c++){
      wm += w[c]*mu[c];
      for(int d=0;d<3;d++) q += w[c]*w[d]*M[c][d];
    }
    double var = q - wm*wm;
    double m = wm + (double)b1[t];
    double sc = (double)g1[t] / sqrt(var + (double)EPSF);
    for(int c=0;c<3;c++) W1f[t*3+c]=(float)(w[c]*sc);
    B1f[t]=(float)(((double)b1[t]-m)*sc + (double)be1[t]);
  }
}

// ---------- layer1: h1 = relu(W1f x + B1f), stored f16 hi/lo [b][n][64] ----------
__global__ void k_layer1(const float* __restrict__ x, const float* __restrict__ W1f,
                         const float* __restrict__ B1f,
                         _Float16* __restrict__ h1h, _Float16* __restrict__ h1l){
  int s = blockIdx.x*256 + threadIdx.x;
  int b = s>>12, n = s&4095;
  const float* xb = x + (size_t)b*12288 + n;
  float x0=xb[0], x1=xb[4096], x2=xb[8192];
  size_t off = ((size_t)((b<<12)+n))<<6;
  #pragma unroll
  for(int q=0;q<8;q++){
    v8h vh, vl;
    #pragma unroll
    for(int e=0;e<8;e++){
      int f=q*8+e;
      float v = fmaf(W1f[f*3+2],x2, fmaf(W1f[f*3+1],x1, fmaf(W1f[f*3],x0, B1f[f])));
      v = v>0.f ? v : 0.f;
      _Float16 hh=(_Float16)v;
      vh[e]=hh;
      vl[e]=(_Float16)(v-(float)hh);
    }
    *(v8h*)(h1h+off+q*8)=vh;
    *(v8h*)(h1l+off+q*8)=vl;
  }
}

// ---------- stats of h1 from f16 planes ----------
__global__ void k_stats1(const _Float16* __restrict__ h1h, const _Float16* __restrict__ h1l,
                         float* __restrict__ partM, float* __restrict__ partMu){
  __shared__ __align__(16) float tl[64][68];
  int t=threadIdx.x, wg=blockIdx.x;
  int s0=wg*256;
  int b=s0>>12, n0=s0&4095;
  int ti=t&15, tj=t>>4;
  float acc[4][4];
  #pragma unroll
  for(int i=0;i<4;i++){
    #pragma unroll
    for(int j=0;j<4;j++) acc[i][j]=0.f;
  }
  float mu=0.f;
  for(int tile=0; tile<4; tile++){
    int nb=n0+tile*64;
    __syncthreads();
    {
      int nr=t>>2, cq=(t&3)<<4;
      const _Float16* ph = h1h + (((size_t)((b<<12)+nb+nr))<<6) + cq;
      const _Float16* pl = h1l + (((size_t)((b<<12)+nb+nr))<<6) + cq;
      #pragma unroll
      for(int q=0;q<2;q++){
        v8h hh=*(const v8h*)(ph+q*8);
        v8h ll=*(const v8h*)(pl+q*8);
        float4 v0=make_float4((float)hh[0]+(float)ll[0],(float)hh[1]+(float)ll[1],
                              (float)hh[2]+(float)ll[2],(float)hh[3]+(float)ll[3]);
        float4 v1=make_float4((float)hh[4]+(float)ll[4],(float)hh[5]+(float)ll[5],
                              (float)hh[6]+(float)ll[6],(float)hh[7]+(float)ll[7]);
        *(float4*)&tl[nr][cq+q*8]   = v0;
        *(float4*)&tl[nr][cq+q*8+4] = v1;
      }
    }
    __syncthreads();
    for(int k=0;k<64;k++){
      float a[4],bb[4];
      #pragma unroll
      for(int i=0;i<4;i++) a[i]=tl[k][i*16+ti];
      #pragma unroll
      for(int j=0;j<4;j++) bb[j]=tl[k][j*16+tj];
      #pragma unroll
      for(int i=0;i<4;i++){
        #pragma unroll
        for(int j=0;j<4;j++) acc[i][j]=fmaf(a[i],bb[j],acc[i][j]);
      }
    }
    if(t<64){
      float ss=0.f;
      for(int k=0;k<64;k++) ss+=tl[k][t];
      mu+=ss;
    }
  }
  #pragma unroll
  for(int i=0;i<4;i++){
    #pragma unroll
    for(int j=0;j<4;j++)
      partM[(size_t)wg*4096+(i*16+ti)*64+(j*16+tj)]=acc[i][j];
  }
  if(t<64) partMu[wg*64+t]=mu;
}

__global__ void k_reduceM1(const float* __restrict__ partM, const float* __restrict__ partMu,
                           float* __restrict__ M1n, float* __restrict__ mu1){
  int e=blockIdx.x*256+threadIdx.x;
  double a=0.0;
  for(int s=0;s<256;s++) a+=(double)partM[(size_t)s*4096+e];
  M1n[e]=(float)(a/65536.0);
  if(e<64){
    double m=0.0;
    for(int s=0;s<256;s++) m+=(double)partMu[s*64+e];
    mu1[e]=(float)(m/65536.0);
  }
}

// ---------- fold layer2: f16 hi/lo weight planes ----------
__global__ void k_fold2(const float* __restrict__ w2, const float* __restrict__ b2,
                        const float* __restrict__ g2, const float* __restrict__ be2,
                        const float* __restrict__ M1n, const float* __restrict__ mu1,
                        _Float16* __restrict__ w2h, _Float16* __restrict__ w2l,
                        float* __restrict__ B2f){
  int f=blockIdx.x, t=threadIdx.x;   // block=64
  __shared__ float w[64];
  w[t]=w2[f*64+t];
  __syncthreads();
  double tm=0.0;
  for(int c=0;c<64;c++) tm += (double)w[c]*(double)M1n[c*64+t];
  double pv=tm*(double)w[t];
  double pm=(double)w[t]*(double)mu1[t];
  #pragma unroll
  for(int off=32;off>0;off>>=1){
    pv+=__shfl_xor(pv,off,64);
    pm+=__shfl_xor(pm,off,64);
  }
  double var=pv-pm*pm;
  double m=pm+(double)b2[f];
  double sc=(double)g2[f]/sqrt(var+(double)EPSF);
  float Wf=(float)((double)w[t]*sc);
  _Float16 hh=(_Float16)Wf;
  w2h[f*64+t]=hh;
  w2l[f*64+t]=(_Float16)(Wf-(float)hh);
  if(t==0) B2f[f]=(float)(((double)b2[f]-m)*sc+(double)be2[f]);
}

// ---------- layer2 MFMA GEMM: h2 = relu(W2 h1 + B2), f16x3 ----------
// grid 2048 = 16b x 2 ftile(64f) x 64 nslice(64n); 4 waves x 16f; 4 iters of 16n.
__global__ __launch_bounds__(256,8) void k_layer2(
    const _Float16* __restrict__ h1h, const _Float16* __restrict__ h1l,
    const _Float16* __restrict__ w2h, const _Float16* __restrict__ w2l,
    const float* __restrict__ B2f,
    _Float16* __restrict__ h2h, _Float16* __restrict__ h2l){
  __shared__ __align__(16) _Float16 stage[4][512];  // [ks*2+plane][slot*8]
  int t=threadIdx.x, wg=blockIdx.x;
  int wv=t>>6, l=t&63;
  int lrow=l&15, lgrp=l>>4;
  int cswz = l ^ ((l>>3)&7);      // involution; preserves lgrp
  int lrow_s=cswz&15, lgrp_s=cswz>>4;
  int b=wg>>7;
  int r=wg&127;
  int f0=(r>>6)<<6;
  int n0=(r&63)<<6;
  // resident A fragments: f = f0 + wv*16 + lrow, k = s*32 + lgrp*8 + e
  v8h Ah[2], Al[2];
  {
    const _Float16* ph = w2h + (size_t)(f0 + wv*16 + lrow)*64 + lgrp*8;
    const _Float16* pl = w2l + (size_t)(f0 + wv*16 + lrow)*64 + lgrp*8;
    #pragma unroll
    for(int s=0;s<2;s++){
      Ah[s]=*(const v8h*)(ph+s*32);
      Al[s]=*(const v8h*)(pl+s*32);
    }
  }
  float bias[4];
  #pragma unroll
  for(int rr=0;rr<4;rr++) bias[rr]=B2f[f0+wv*16+lgrp*4+rr];
  // staging: wave wv stages combo wv (ks=wv>>1, plane=wv&1); pre-swizzled source
  int ks=wv>>1, pln=wv&1;
  const _Float16* src = (pln ? h1l : h1h)
      + (((size_t)((b<<12)+n0+lrow_s))<<6) + ks*32 + lgrp_s*8;
  _Float16* dst = &stage[wv][0];
  for(int it=0; it<4; it++){
    GLL(src,dst);
    src += 1024;   // 16 n rows * 64 f16
    __syncthreads();
    v8h Bh[2],Bl[2];
    #pragma unroll
    for(int s=0;s<2;s++){
      Bh[s]=*(const v8h*)&stage[s*2  ][cswz*8];
      Bl[s]=*(const v8h*)&stage[s*2+1][cswz*8];
    }
    v4f acc={bias[0],bias[1],bias[2],bias[3]};
    #pragma unroll
    for(int s=0;s<2;s++){
      acc=__builtin_amdgcn_mfma_f32_16x16x32_f16(Ah[s],Bh[s],acc,0,0,0);
      acc=__builtin_amdgcn_mfma_f32_16x16x32_f16(Ah[s],Bl[s],acc,0,0,0);
      acc=__builtin_amdgcn_mfma_f32_16x16x32_f16(Al[s],Bh[s],acc,0,0,0);
    }
    // C: col(n)=lrow, row(f)=lgrp*4+rr ; relu + hi/lo split, 8B stores
    int n=n0+it*16+lrow;
    size_t o=(((size_t)((b<<12)+n))<<7) + f0 + wv*16 + lgrp*4;
    v4h sh, sl4;
    #pragma unroll
    for(int rr=0;rr<4;rr++){
      float v=acc[rr];
      v = v>0.f ? v : 0.f;
      _Float16 hh=(_Float16)v;
      sh[rr]=hh;
      sl4[rr]=(_Float16)(v-(float)hh);
    }
    *(v4h*)(h2h+o)=sh;
    *(v4h*)(h2l+o)=sl4;
    __syncthreads();
  }
}

// ---------- stats of h2 from f16 planes ----------
__global__ void k_stats2(const _Float16* __restrict__ h2h, const _Float16* __restrict__ h2l,
                         float* __restrict__ partM, float* __restrict__ partMu){
  __shared__ __align__(16) float tl[64][132];
  int t=threadIdx.x, wg=blockIdx.x;
  int s0=wg*256;
  int b=s0>>12, n0=s0&4095;
  int ti=t&15, tj=t>>4;
  float acc[8][8];
  #pragma unroll
  for(int i=0;i<8;i++){
    #pragma unroll
    for(int j=0;j<8;j++) acc[i][j]=0.f;
  }
  float mu=0.f;
  for(int tile=0; tile<4; tile++){
    int nb=n0+tile*64;
    __syncthreads();
    {
      int nr=t>>2, cq=(t&3)<<5;
      const _Float16* ph = h2h + ((size_t)((b<<12)+nb+nr))*128 + cq;
      const _Float16* pl = h2l + ((size_t)((b<<12)+nb+nr))*128 + cq;
      #pragma unroll
      for(int q=0;q<4;q++){
        v8h hh=*(const v8h*)(ph+q*8);
        v8h ll=*(const v8h*)(pl+q*8);
        float4 v0=make_float4((float)hh[0]+(float)ll[0],(float)hh[1]+(float)ll[1],
                              (float)hh[2]+(float)ll[2],(float)hh[3]+(float)ll[3]);
        float4 v1=make_float4((float)hh[4]+(float)ll[4],(float)hh[5]+(float)ll[5],
                              (float)hh[6]+(float)ll[6],(float)hh[7]+(float)ll[7]);
        *(float4*)&tl[nr][cq+q*8]   = v0;
        *(float4*)&tl[nr][cq+q*8+4] = v1;
      }
    }
    __syncthreads();
    for(int k=0;k<64;k++){
      float a[8],bb[8];
      #pragma unroll
      for(int i=0;i<8;i++) a[i]=tl[k][i*16+ti];
      #pragma unroll
      for(int j=0;j<8;j++) bb[j]=tl[k][j*16+tj];
      #pragma unroll
      for(int i=0;i<8;i++){
        #pragma unroll
        for(int j=0;j<8;j++) acc[i][j]=fmaf(a[i],bb[j],acc[i][j]);
      }
    }
    if(t<128){
      float s=0.f;
      for(int k=0;k<64;k++) s+=tl[k][t];
      mu+=s;
    }
  }
  #pragma unroll
  for(int i=0;i<8;i++){
    #pragma unroll
    for(int j=0;j<8;j++)
      partM[(size_t)wg*16384+(i*16+ti)*128+(j*16+tj)]=acc[i][j];
  }
  if(t<128) partMu[wg*128+t]=mu;
}

__global__ void k_reduceM2(const float* __restrict__ partM, const float* __restrict__ partMu,
                           float* __restrict__ M2n, float* __restrict__ mu2){
  int e=blockIdx.x*256+threadIdx.x;
  double a=0.0;
  for(int s=0;s<256;s++) a+=(double)partM[(size_t)s*16384+e];
  M2n[e]=(float)(a/65536.0);
  if(e<128){
    double m=0.0;
    for(int s=0;s<256;s++) m+=(double)partMu[s*128+e];
    mu2[e]=(float)(m/65536.0);
  }
}

// ---------- fold layer3: f16 hi/lo weight planes ----------
__global__ void k_fold3(const float* __restrict__ w3, const float* __restrict__ b3,
                        const float* __restrict__ g3, const float* __restrict__ be3,
                        const float* __restrict__ M2n, const float* __restrict__ mu2,
                        _Float16* __restrict__ w3h, _Float16* __restrict__ w3l,
                        float* __restrict__ B3f){
  int f=blockIdx.x, t=threadIdx.x;
  __shared__ float w[128];
  __shared__ double rv[2], rm[2];
  w[t]=w3[f*128+t];
  __syncthreads();
  double tm=0.0;
  for(int c=0;c<128;c++) tm += (double)w[c]*(double)M2n[c*128+t];
  double pv=tm*(double)w[t];
  double pm=(double)w[t]*(double)mu2[t];
  #pragma unroll
  for(int off=32;off>0;off>>=1){
    pv+=__shfl_xor(pv,off,64);
    pm+=__shfl_xor(pm,off,64);
  }
  if((t&63)==0){ rv[t>>6]=pv; rm[t>>6]=pm; }
  __syncthreads();
  double pmt=rm[0]+rm[1];
  double var=(rv[0]+rv[1]) - pmt*pmt;
  double m=pmt + (double)b3[f];
  double sc=(double)g3[f]/sqrt(var+(double)EPSF);
  float Wf=(float)((double)w[t]*sc);
  _Float16 hh=(_Float16)Wf;
  w3h[f*128+t]=hh;
  w3l[f*128+t]=(_Float16)(Wf-(float)hh);
  if(t==0) B3f[f]=(float)(((double)b3[f]-m)*sc+(double)be3[f]);
}

// ---------- layer3 MFMA GEMM fused with histogram (8 blocks/CU, swizzled) ----------
// grid 2048 = 16b x 16 ftile(64f) x 8 nslice(512n); 4 waves, wave wv = 16 f rows.
__global__ __launch_bounds__(256,8) void k_gemm3_hist(
    const _Float16* __restrict__ h2h, const _Float16* __restrict__ h2l,
    const _Float16* __restrict__ w3h, const _Float16* __restrict__ w3l,
    const float* __restrict__ B3f, unsigned int* __restrict__ hist){
  __shared__ __align__(16) _Float16 stage[8][512];  // [kstep*2+plane][slot*8]
  __shared__ unsigned int lh[2240];                 // 64ch x 70 bins, u16-packed
  int t=threadIdx.x, wg=blockIdx.x;
  int wv=t>>6, l=t&63;
  int lrow=l&15, lgrp=l>>4;
  int cswz = l ^ ((l>>3)&7);
  int lrow_s=cswz&15, lgrp_s=cswz>>4;
  int b=wg>>7;
  int r=wg&127;
  int f0=(r>>3)<<6;
  int sl=r&7;
  int base=70*((b<<10)+f0);
  for(int i=t;i<2240;i+=256) lh[i]=0u;

  // resident A fragments: f = f0 + wv*16 + lrow, k = s*32 + lgrp*8 + e
  v8h Ah[4], Al[4];
  {
    const _Float16* ph = w3h + (size_t)(f0 + wv*16 + lrow)*128 + lgrp*8;
    const _Float16* pl = w3l + (size_t)(f0 + wv*16 + lrow)*128 + lgrp*8;
    #pragma unroll
    for(int s=0;s<4;s++){
      Ah[s]=*(const v8h*)(ph+s*32);
      Al[s]=*(const v8h*)(pl+s*32);
    }
  }
  float bias[4]; int base70[4];
  #pragma unroll
  for(int rr=0;rr<4;rr++){
    int fl_=wv*16+lgrp*4+rr;
    bias[rr]=B3f[f0+fl_];
    base70[rr]=fl_*70;
  }
  const float wbin=(10.0f-(-10.0f))/70.0f;
  const float inv_w=1.0f/wbin;
  const float off_w=10.0f*inv_w;

  // staging: wave wv stages kstep s=wv, both planes; pre-swizzled source
  const _Float16* pH = h2h + ((size_t)((b<<12)+sl*512+lrow_s))*128 + wv*32 + lgrp_s*8;
  const _Float16* pL = h2l + ((size_t)((b<<12)+sl*512+lrow_s))*128 + wv*32 + lgrp_s*8;
  _Float16* dstH = &stage[wv*2  ][0];
  _Float16* dstL = &stage[wv*2+1][0];

  for(int i=0;i<32;i++){
    GLL(pH,dstH);
    GLL(pL,dstL);
    pH += 2048; pL += 2048;
    __syncthreads();   // drains vmcnt -> staged data visible to all waves

    v8h Bh[4], Bl[4];
    #pragma unroll
    for(int s=0;s<4;s++){
      Bh[s]=*(const v8h*)&stage[s*2  ][cswz*8];
      Bl[s]=*(const v8h*)&stage[s*2+1][cswz*8];
    }
    v4f acc={bias[0],bias[1],bias[2],bias[3]};
    #pragma unroll
    for(int s=0;s<4;s++){
      acc=__builtin_amdgcn_mfma_f32_16x16x32_f16(Ah[s],Bh[s],acc,0,0,0);
      acc=__builtin_amdgcn_mfma_f32_16x16x32_f16(Ah[s],Bl[s],acc,0,0,0);
      acc=__builtin_amdgcn_mfma_f32_16x16x32_f16(Al[s],Bh[s],acc,0,0,0);
    }
    // epilogue: row(f)=lgrp*4+rr; bin and count (exact leak semantics)
    #pragma unroll
    for(int rr=0;rr<4;rr++){
      float q=fmaf(acc[rr],inv_w,off_w);
      if(q>-2.0e9f && q<2.0e9f){
        int bin=(int)floorf(q);
        int loc=base70[rr]+bin;
        if((unsigned)loc<4480u){
          atomicAdd(&lh[loc>>1], 1u<<((loc&1)<<4));
        }else{
          int g=base+loc;
          if(g>=0 && g<TOTBINS) atomicAdd(&hist[g],1u);
        }
      }
    }
    __syncthreads();   // reads done before next stage overwrites
  }
  for(int i=t;i<2240;i+=256){
    unsigned int c=lh[i];
    if(c&0xFFFFu) atomicAdd(&hist[base+2*i],   c&0xFFFFu);
    if(c>>16)     atomicAdd(&hist[base+2*i+1], c>>16);
  }
}

__global__ void k_argmax(const unsigned int* __restrict__ hist, float* __restrict__ out){
  int g = blockIdx.x*256 + threadIdx.x;
  const unsigned int* h = hist + (size_t)g*70;
  unsigned int best=h[0]; int arg=0;
  for(int k=1;k<70;k++){
    unsigned int c=h[k];
    if(c>best){ best=c; arg=k; }
  }
  out[g]=(float)arg;
}

extern "C" void kernel_launch(void* const* d_in, const int* in_sizes, int n_in,
                              void* d_out, int out_size, void* d_ws, size_t ws_size,
                              hipStream_t stream){
  const float* x  =(const float*)d_in[0];
  const float* w1 =(const float*)d_in[1];
  const float* b1 =(const float*)d_in[2];
  const float* g1 =(const float*)d_in[3];
  const float* be1=(const float*)d_in[4];
  const float* w2 =(const float*)d_in[5];
  const float* b2 =(const float*)d_in[6];
  const float* g2 =(const float*)d_in[7];
  const float* be2=(const float*)d_in[8];
  const float* w3 =(const float*)d_in[9];
  const float* b3 =(const float*)d_in[10];
  const float* g3 =(const float*)d_in[11];
  const float* be3=(const float*)d_in[12];

  float* ws=(float*)d_ws;
  unsigned int* hist=(unsigned int*)ws;
  float* partX = ws+OFF_PARTX;
  float* W1f   = ws+OFF_W1F;
  float* B1f   = ws+OFF_B1F;
  float* pMu1  = ws+OFF_PMU1;
  float* M1n   = ws+OFF_M1N;
  float* mu1   = ws+OFF_MU1;
  _Float16* w2h=(_Float16*)(ws+OFF_W2H);
  _Float16* w2l=(_Float16*)(ws+OFF_W2L);
  float* B2f   = ws+OFF_B2F;
  float* pMu2  = ws+OFF_PMU2;
  float* M2n   = ws+OFF_M2N;
  float* mu2   = ws+OFF_MU2;
  _Float16* w3h=(_Float16*)(ws+OFF_W3H);
  _Float16* w3l=(_Float16*)(ws+OFF_W3L);
  float* B3f   = ws+OFF_B3F;
  _Float16* h1h=(_Float16*)(ws+OFF_H1H);
  _Float16* h1l=(_Float16*)(ws+OFF_H1L);
  _Float16* h2h=(_Float16*)(ws+OFF_H2H);
  _Float16* h2l=(_Float16*)(ws+OFF_H2L);
  float* partM1=(float*)(ws+OFF_H2H);   // h2 region free until k_layer2
  float* partM2=(float*)(ws+OFF_H1H);   // h1 region free after k_layer2

  hipMemsetAsync(hist, 0, (size_t)TOTBINS*sizeof(unsigned int), stream);

  k_statsX  <<<256,256,0,stream>>>(x, partX);
  k_fold1   <<<1,  256,0,stream>>>(partX,w1,b1,g1,be1,W1f,B1f);
  k_layer1  <<<256,256,0,stream>>>(x,W1f,B1f,h1h,h1l);
  k_stats1  <<<256,256,0,stream>>>(h1h,h1l,partM1,pMu1);
  k_reduceM1<<<16, 256,0,stream>>>(partM1,pMu1,M1n,mu1);
  k_fold2   <<<128, 64,0,stream>>>(w2,b2,g2,be2,M1n,mu1,w2h,w2l,B2f);
  k_layer2  <<<2048,256,0,stream>>>(h1h,h1l,w2h,w2l,B2f,h2h,h2l);
  k_stats2  <<<256,256,0,stream>>>(h2h,h2l,partM2,pMu2);
  k_reduceM2<<<64, 256,0,stream>>>(partM2,pMu2,M2n,mu2);
  k_fold3   <<<1024,128,0,stream>>>(w3,b3,g3,be3,M2n,mu2,w3h,w3l,B3f);
  k_gemm3_hist<<<2048,256,0,stream>>>(h2h,h2l,w3h,w3l,B3f,hist);
  k_argmax  <<<64, 256,0,stream>>>(hist,(float*)d_out);
}

// Round 8
// 251.500 us; speedup vs baseline: 1.6409x; 1.0433x over previous
//
#include <hip/hip_runtime.h>

#define EPSF 1e-5f
#define TOTBINS 1146880   // 70*16*1024

typedef _Float16 v8h __attribute__((ext_vector_type(8)));
typedef _Float16 v4h __attribute__((ext_vector_type(4)));
typedef float v4f __attribute__((ext_vector_type(4)));

// ---- workspace offsets (in float slots) ----
#define OFF_PARTX   1146880
#define OFF_W1F     1149952
#define OFF_B1F     1150144
#define OFF_PMU1    1150208
#define OFF_M1N     1166592
#define OFF_MU1     1170688
#define OFF_W2H     1170752   // 128x64 f16 = 8192 halves = 4096 float slots
#define OFF_W2L     1174848
#define OFF_B2F     1178944
#define OFF_PMU2    1179072
#define OFF_M2N     1211840
#define OFF_MU2     1228224
#define OFF_W3H     1228352   // 1024x128 f16 = 131072 halves = 65536 float slots
#define OFF_W3L     1293888
#define OFF_B3F     1359424
#define OFF_H1H     1360448   // 16*4096*64 f16 = 2097152 float slots
#define OFF_H1L     3457600   // (h1h..h1l region reused as partM2 after layer2)
#define OFF_H2H     5554752   // 16*4096*128 f16 = 4194304 float slots; reused as partM1 early
#define OFF_H2L     9749056   // ends 13943360 (55.8 MB)

#define GLL(src,dst) __builtin_amdgcn_global_load_lds( \
    (const __attribute__((address_space(1))) void*)(src), \
    (__attribute__((address_space(3))) void*)(dst), 16, 0, 0)

// ---------- stats of x ----------
__global__ void k_statsX(const float* __restrict__ x, float* __restrict__ part){
  __shared__ float red[12][256];
  int t = threadIdx.x;
  int s = blockIdx.x*256 + t;
  int b = s >> 12, n = s & 4095;
  const float* xb = x + (size_t)b*12288 + n;
  float x0 = xb[0], x1 = xb[4096], x2 = xb[8192];
  float v[12] = {x0,x1,x2, x0*x0,x0*x1,x0*x2, x1*x1,x1*x2,x2*x2, 0.f,0.f,0.f};
  #pragma unroll
  for(int j=0;j<12;j++) red[j][t]=v[j];
  __syncthreads();
  for(int off=128; off>0; off>>=1){
    if(t<off){
      #pragma unroll
      for(int j=0;j<12;j++) red[j][t]+=red[j][t+off];
    }
    __syncthreads();
  }
  if(t<12) part[blockIdx.x*12+t]=red[t][0];
}

__global__ void k_fold1(const float* __restrict__ part,
                        const float* __restrict__ w1, const float* __restrict__ b1,
                        const float* __restrict__ g1, const float* __restrict__ be1,
                        float* __restrict__ W1f, float* __restrict__ B1f){
  __shared__ double S[12];
  int t=threadIdx.x;
  if(t<12){
    double a=0.0;
    for(int s=0;s<256;s++) a+=(double)part[s*12+t];
    S[t]=a;
  }
  __syncthreads();
  if(t<64){
    double inv = 1.0/65536.0;
    double mu[3]={S[0]*inv,S[1]*inv,S[2]*inv};
    double M[3][3];
    M[0][0]=S[3]*inv; M[0][1]=S[4]*inv; M[0][2]=S[5]*inv;
    M[1][1]=S[6]*inv; M[1][2]=S[7]*inv; M[2][2]=S[8]*inv;
    M[1][0]=M[0][1]; M[2][0]=M[0][2]; M[2][1]=M[1][2];
    double w[3]={(double)w1[t*3],(double)w1[t*3+1],(double)w1[t*3+2]};
    double wm=0.0, q=0.0;
    for(int c=0;c<3;c++){
      wm += w[c]*mu[c];
      for(int d=0;d<3;d++) q += w[c]*w[d]*M[c][d];
    }
    double var = q - wm*wm;
    double m = wm + (double)b1[t];
    double sc = (double)g1[t] / sqrt(var + (double)EPSF);
    for(int c=0;c<3;c++) W1f[t*3+c]=(float)(w[c]*sc);
    B1f[t]=(float)(((double)b1[t]-m)*sc + (double)be1[t]);
  }
}

// ---------- layer1: h1 = relu(W1f x + B1f), stored f16 hi/lo [b][n][64] ----------
__global__ void k_layer1(const float* __restrict__ x, const float* __restrict__ W1f,
                         const float* __restrict__ B1f,
                         _Float16* __restrict__ h1h, _Float16* __restrict__ h1l){
  int s = blockIdx.x*256 + threadIdx.x;
  int b = s>>12, n = s&4095;
  const float* xb = x + (size_t)b*12288 + n;
  float x0=xb[0], x1=xb[4096], x2=xb[8192];
  size_t off = ((size_t)((b<<12)+n))<<6;
  #pragma unroll
  for(int q=0;q<8;q++){
    v8h vh, vl;
    #pragma unroll
    for(int e=0;e<8;e++){
      int f=q*8+e;
      float v = fmaf(W1f[f*3+2],x2, fmaf(W1f[f*3+1],x1, fmaf(W1f[f*3],x0, B1f[f])));
      v = v>0.f ? v : 0.f;
      _Float16 hh=(_Float16)v;
      vh[e]=hh;
      vl[e]=(_Float16)(v-(float)hh);
    }
    *(v8h*)(h1h+off+q*8)=vh;
    *(v8h*)(h1l+off+q*8)=vl;
  }
}

// ---------- stats of h1 from f16 planes ----------
__global__ void k_stats1(const _Float16* __restrict__ h1h, const _Float16* __restrict__ h1l,
                         float* __restrict__ partM, float* __restrict__ partMu){
  __shared__ __align__(16) float tl[64][68];
  int t=threadIdx.x, wg=blockIdx.x;
  int s0=wg*256;
  int b=s0>>12, n0=s0&4095;
  int ti=t&15, tj=t>>4;
  float acc[4][4];
  #pragma unroll
  for(int i=0;i<4;i++){
    #pragma unroll
    for(int j=0;j<4;j++) acc[i][j]=0.f;
  }
  float mu=0.f;
  for(int tile=0; tile<4; tile++){
    int nb=n0+tile*64;
    __syncthreads();
    {
      int nr=t>>2, cq=(t&3)<<4;
      const _Float16* ph = h1h + (((size_t)((b<<12)+nb+nr))<<6) + cq;
      const _Float16* pl = h1l + (((size_t)((b<<12)+nb+nr))<<6) + cq;
      #pragma unroll
      for(int q=0;q<2;q++){
        v8h hh=*(const v8h*)(ph+q*8);
        v8h ll=*(const v8h*)(pl+q*8);
        float4 v0=make_float4((float)hh[0]+(float)ll[0],(float)hh[1]+(float)ll[1],
                              (float)hh[2]+(float)ll[2],(float)hh[3]+(float)ll[3]);
        float4 v1=make_float4((float)hh[4]+(float)ll[4],(float)hh[5]+(float)ll[5],
                              (float)hh[6]+(float)ll[6],(float)hh[7]+(float)ll[7]);
        *(float4*)&tl[nr][cq+q*8]   = v0;
        *(float4*)&tl[nr][cq+q*8+4] = v1;
      }
    }
    __syncthreads();
    for(int k=0;k<64;k++){
      float a[4],bb[4];
      #pragma unroll
      for(int i=0;i<4;i++) a[i]=tl[k][i*16+ti];
      #pragma unroll
      for(int j=0;j<4;j++) bb[j]=tl[k][j*16+tj];
      #pragma unroll
      for(int i=0;i<4;i++){
        #pragma unroll
        for(int j=0;j<4;j++) acc[i][j]=fmaf(a[i],bb[j],acc[i][j]);
      }
    }
    if(t<64){
      float ss=0.f;
      for(int k=0;k<64;k++) ss+=tl[k][t];
      mu+=ss;
    }
  }
  #pragma unroll
  for(int i=0;i<4;i++){
    #pragma unroll
    for(int j=0;j<4;j++)
      partM[(size_t)wg*4096+(i*16+ti)*64+(j*16+tj)]=acc[i][j];
  }
  if(t<64) partMu[wg*64+t]=mu;
}

__global__ void k_reduceM1(const float* __restrict__ partM, const float* __restrict__ partMu,
                           float* __restrict__ M1n, float* __restrict__ mu1){
  int e=blockIdx.x*256+threadIdx.x;
  double a=0.0;
  for(int s=0;s<256;s++) a+=(double)partM[(size_t)s*4096+e];
  M1n[e]=(float)(a/65536.0);
  if(e<64){
    double m=0.0;
    for(int s=0;s<256;s++) m+=(double)partMu[s*64+e];
    mu1[e]=(float)(m/65536.0);
  }
}

// ---------- fold layer2: f16 hi/lo weight planes ----------
__global__ void k_fold2(const float* __restrict__ w2, const float* __restrict__ b2,
                        const float* __restrict__ g2, const float* __restrict__ be2,
                        const float* __restrict__ M1n, const float* __restrict__ mu1,
                        _Float16* __restrict__ w2h, _Float16* __restrict__ w2l,
                        float* __restrict__ B2f){
  int f=blockIdx.x, t=threadIdx.x;   // block=64
  __shared__ float w[64];
  w[t]=w2[f*64+t];
  __syncthreads();
  double tm=0.0;
  for(int c=0;c<64;c++) tm += (double)w[c]*(double)M1n[c*64+t];
  double pv=tm*(double)w[t];
  double pm=(double)w[t]*(double)mu1[t];
  #pragma unroll
  for(int off=32;off>0;off>>=1){
    pv+=__shfl_xor(pv,off,64);
    pm+=__shfl_xor(pm,off,64);
  }
  double var=pv-pm*pm;
  double m=pm+(double)b2[f];
  double sc=(double)g2[f]/sqrt(var+(double)EPSF);
  float Wf=(float)((double)w[t]*sc);
  _Float16 hh=(_Float16)Wf;
  w2h[f*64+t]=hh;
  w2l[f*64+t]=(_Float16)(Wf-(float)hh);
  if(t==0) B2f[f]=(float)(((double)b2[f]-m)*sc+(double)be2[f]);
}

// ---------- layer2 MFMA GEMM: h2 = relu(W2 h1 + B2), f16x3 ----------
// grid 2048 = 16b x 2 ftile(64f) x 64 nslice(64n); 4 waves x 16f; 4 iters of 16n.
__global__ __launch_bounds__(256,8) void k_layer2(
    const _Float16* __restrict__ h1h, const _Float16* __restrict__ h1l,
    const _Float16* __restrict__ w2h, const _Float16* __restrict__ w2l,
    const float* __restrict__ B2f,
    _Float16* __restrict__ h2h, _Float16* __restrict__ h2l){
  __shared__ __align__(16) _Float16 stage[4][512];  // [ks*2+plane][slot*8]
  int t=threadIdx.x, wg=blockIdx.x;
  int wv=t>>6, l=t&63;
  int lrow=l&15, lgrp=l>>4;
  int b=wg>>7;
  int r=wg&127;
  int f0=(r>>6)<<6;
  int n0=(r&63)<<6;
  // resident A fragments: f = f0 + wv*16 + lrow, k = s*32 + lgrp*8 + e
  v8h Ah[2], Al[2];
  {
    const _Float16* ph = w2h + (size_t)(f0 + wv*16 + lrow)*64 + lgrp*8;
    const _Float16* pl = w2l + (size_t)(f0 + wv*16 + lrow)*64 + lgrp*8;
    #pragma unroll
    for(int s=0;s<2;s++){
      Ah[s]=*(const v8h*)(ph+s*32);
      Al[s]=*(const v8h*)(pl+s*32);
    }
  }
  float bias[4];
  #pragma unroll
  for(int rr=0;rr<4;rr++) bias[rr]=B2f[f0+wv*16+lgrp*4+rr];
  // staging: wave wv stages combo wv (ks=wv>>1, plane=wv&1)
  int ks=wv>>1, pln=wv&1;
  const _Float16* src = (pln ? h1l : h1h)
      + (((size_t)((b<<12)+n0+lrow))<<6) + ks*32 + lgrp*8;
  _Float16* dst = &stage[wv][0];
  for(int it=0; it<4; it++){
    GLL(src,dst);
    src += 1024;   // 16 n rows * 64 f16
    __syncthreads();
    v8h Bh[2],Bl[2];
    #pragma unroll
    for(int s=0;s<2;s++){
      Bh[s]=*(const v8h*)&stage[s*2  ][l*8];
      Bl[s]=*(const v8h*)&stage[s*2+1][l*8];
    }
    v4f acc={bias[0],bias[1],bias[2],bias[3]};
    #pragma unroll
    for(int s=0;s<2;s++){
      acc=__builtin_amdgcn_mfma_f32_16x16x32_f16(Ah[s],Bh[s],acc,0,0,0);
      acc=__builtin_amdgcn_mfma_f32_16x16x32_f16(Ah[s],Bl[s],acc,0,0,0);
      acc=__builtin_amdgcn_mfma_f32_16x16x32_f16(Al[s],Bh[s],acc,0,0,0);
    }
    // C: col(n)=lrow, row(f)=lgrp*4+rr ; relu + hi/lo split, 8B stores
    int n=n0+it*16+lrow;
    size_t o=(((size_t)((b<<12)+n))<<7) + f0 + wv*16 + lgrp*4;
    v4h sh, sl4;
    #pragma unroll
    for(int rr=0;rr<4;rr++){
      float v=acc[rr];
      v = v>0.f ? v : 0.f;
      _Float16 hh=(_Float16)v;
      sh[rr]=hh;
      sl4[rr]=(_Float16)(v-(float)hh);
    }
    *(v4h*)(h2h+o)=sh;
    *(v4h*)(h2l+o)=sl4;
    __syncthreads();
  }
}

// ---------- stats of h2 from f16 planes ----------
__global__ void k_stats2(const _Float16* __restrict__ h2h, const _Float16* __restrict__ h2l,
                         float* __restrict__ partM, float* __restrict__ partMu){
  __shared__ __align__(16) float tl[64][132];
  int t=threadIdx.x, wg=blockIdx.x;
  int s0=wg*256;
  int b=s0>>12, n0=s0&4095;
  int ti=t&15, tj=t>>4;
  float acc[8][8];
  #pragma unroll
  for(int i=0;i<8;i++){
    #pragma unroll
    for(int j=0;j<8;j++) acc[i][j]=0.f;
  }
  float mu=0.f;
  for(int tile=0; tile<4; tile++){
    int nb=n0+tile*64;
    __syncthreads();
    {
      int nr=t>>2, cq=(t&3)<<5;
      const _Float16* ph = h2h + ((size_t)((b<<12)+nb+nr))*128 + cq;
      const _Float16* pl = h2l + ((size_t)((b<<12)+nb+nr))*128 + cq;
      #pragma unroll
      for(int q=0;q<4;q++){
        v8h hh=*(const v8h*)(ph+q*8);
        v8h ll=*(const v8h*)(pl+q*8);
        float4 v0=make_float4((float)hh[0]+(float)ll[0],(float)hh[1]+(float)ll[1],
                              (float)hh[2]+(float)ll[2],(float)hh[3]+(float)ll[3]);
        float4 v1=make_float4((float)hh[4]+(float)ll[4],(float)hh[5]+(float)ll[5],
                              (float)hh[6]+(float)ll[6],(float)hh[7]+(float)ll[7]);
        *(float4*)&tl[nr][cq+q*8]   = v0;
        *(float4*)&tl[nr][cq+q*8+4] = v1;
      }
    }
    __syncthreads();
    for(int k=0;k<64;k++){
      float a[8],bb[8];
      #pragma unroll
      for(int i=0;i<8;i++) a[i]=tl[k][i*16+ti];
      #pragma unroll
      for(int j=0;j<8;j++) bb[j]=tl[k][j*16+tj];
      #pragma unroll
      for(int i=0;i<8;i++){
        #pragma unroll
        for(int j=0;j<8;j++) acc[i][j]=fmaf(a[i],bb[j],acc[i][j]);
      }
    }
    if(t<128){
      float s=0.f;
      for(int k=0;k<64;k++) s+=tl[k][t];
      mu+=s;
    }
  }
  #pragma unroll
  for(int i=0;i<8;i++){
    #pragma unroll
    for(int j=0;j<8;j++)
      partM[(size_t)wg*16384+(i*16+ti)*128+(j*16+tj)]=acc[i][j];
  }
  if(t<128) partMu[wg*128+t]=mu;
}

__global__ void k_reduceM2(const float* __restrict__ partM, const float* __restrict__ partMu,
                           float* __restrict__ M2n, float* __restrict__ mu2){
  int e=blockIdx.x*256+threadIdx.x;
  double a=0.0;
  for(int s=0;s<256;s++) a+=(double)partM[(size_t)s*16384+e];
  M2n[e]=(float)(a/65536.0);
  if(e<128){
    double m=0.0;
    for(int s=0;s<256;s++) m+=(double)partMu[s*128+e];
    mu2[e]=(float)(m/65536.0);
  }
}

// ---------- fold layer3: f16 hi/lo weight planes ----------
__global__ void k_fold3(const float* __restrict__ w3, const float* __restrict__ b3,
                        const float* __restrict__ g3, const float* __restrict__ be3,
                        const float* __restrict__ M2n, const float* __restrict__ mu2,
                        _Float16* __restrict__ w3h, _Float16* __restrict__ w3l,
                        float* __restrict__ B3f){
  int f=blockIdx.x, t=threadIdx.x;
  __shared__ float w[128];
  __shared__ double rv[2], rm[2];
  w[t]=w3[f*128+t];
  __syncthreads();
  double tm=0.0;
  for(int c=0;c<128;c++) tm += (double)w[c]*(double)M2n[c*128+t];
  double pv=tm*(double)w[t];
  double pm=(double)w[t]*(double)mu2[t];
  #pragma unroll
  for(int off=32;off>0;off>>=1){
    pv+=__shfl_xor(pv,off,64);
    pm+=__shfl_xor(pm,off,64);
  }
  if((t&63)==0){ rv[t>>6]=pv; rm[t>>6]=pm; }
  __syncthreads();
  double pmt=rm[0]+rm[1];
  double var=(rv[0]+rv[1]) - pmt*pmt;
  double m=pmt + (double)b3[f];
  double sc=(double)g3[f]/sqrt(var+(double)EPSF);
  float Wf=(float)((double)w[t]*sc);
  _Float16 hh=(_Float16)Wf;
  w3h[f*128+t]=hh;
  w3l[f*128+t]=(_Float16)(Wf-(float)hh);
  if(t==0) B3f[f]=(float)(((double)b3[f]-m)*sc+(double)be3[f]);
}

// ---------- layer3 MFMA GEMM fused with histogram ----------
// grid 1024 = 16b x 8 ftile(128f) x 8 nslice(512n); 4 waves x 32f (two 16f tiles).
// Double-buffered stage, early GLL issue, ONE barrier per 16-n iter.
__global__ __launch_bounds__(256,4) void k_gemm3_hist(
    const _Float16* __restrict__ h2h, const _Float16* __restrict__ h2l,
    const _Float16* __restrict__ w3h, const _Float16* __restrict__ w3l,
    const float* __restrict__ B3f, unsigned int* __restrict__ hist){
  __shared__ __align__(16) _Float16 stage[2][8][512];  // [buf][kstep*2+plane][lane*8]
  __shared__ unsigned int lh[4480];                    // 128ch x 70 bins, u16-packed
  int t=threadIdx.x, wg=blockIdx.x;
  int wv=t>>6, l=t&63;
  int lrow=l&15, lgrp=l>>4;
  int b=wg>>6;
  int r=wg&63;
  int f0=(r>>3)<<7;     // 8 ftiles of 128
  int sl=r&7;           // 8 slices of 512 n
  int base=70*((b<<10)+f0);
  for(int i=t;i<4480;i+=256) lh[i]=0u;

  // resident A fragments, two 16-f tiles per wave:
  // f = f0 + wv*32 + T*16 + lrow, k = s*32 + lgrp*8 + e
  v8h Ah[2][4], Al[2][4];
  #pragma unroll
  for(int T=0;T<2;T++){
    const _Float16* ph = w3h + (size_t)(f0 + wv*32 + T*16 + lrow)*128 + lgrp*8;
    const _Float16* pl = w3l + (size_t)(f0 + wv*32 + T*16 + lrow)*128 + lgrp*8;
    #pragma unroll
    for(int s=0;s<4;s++){
      Ah[T][s]=*(const v8h*)(ph+s*32);
      Al[T][s]=*(const v8h*)(pl+s*32);
    }
  }
  float bias[2][4]; int base70[2][4];
  #pragma unroll
  for(int T=0;T<2;T++){
    #pragma unroll
    for(int rr=0;rr<4;rr++){
      int fl_=wv*32+T*16+lgrp*4+rr;
      bias[T][rr]=B3f[f0+fl_];
      base70[T][rr]=fl_*70;
    }
  }
  const float wbin=(10.0f-(-10.0f))/70.0f;
  const float inv_w=1.0f/wbin;
  const float off_w=10.0f*inv_w;

  // staging: wave wv stages kstep s=wv, both planes; n-row = lrow
  const _Float16* pH = h2h + ((size_t)((b<<12)+sl*512+lrow))*128 + wv*32 + lgrp*8;
  const _Float16* pL = h2l + ((size_t)((b<<12)+sl*512+lrow))*128 + wv*32 + lgrp*8;

#define ISSUE(B_) { GLL(pH,&stage[B_][wv*2][0]); GLL(pL,&stage[B_][wv*2+1][0]); \
                    pH+=2048; pL+=2048; }
#define COMPUTE(B_) { \
    v4f acc0={bias[0][0],bias[0][1],bias[0][2],bias[0][3]}; \
    v4f acc1={bias[1][0],bias[1][1],bias[1][2],bias[1][3]}; \
    _Pragma("unroll") \
    for(int s=0;s<4;s++){ \
      v8h Bh=*(const v8h*)&stage[B_][s*2  ][l*8]; \
      v8h Bl=*(const v8h*)&stage[B_][s*2+1][l*8]; \
      acc0=__builtin_amdgcn_mfma_f32_16x16x32_f16(Ah[0][s],Bh,acc0,0,0,0); \
      acc0=__builtin_amdgcn_mfma_f32_16x16x32_f16(Ah[0][s],Bl,acc0,0,0,0); \
      acc0=__builtin_amdgcn_mfma_f32_16x16x32_f16(Al[0][s],Bh,acc0,0,0,0); \
      acc1=__builtin_amdgcn_mfma_f32_16x16x32_f16(Ah[1][s],Bh,acc1,0,0,0); \
      acc1=__builtin_amdgcn_mfma_f32_16x16x32_f16(Ah[1][s],Bl,acc1,0,0,0); \
      acc1=__builtin_amdgcn_mfma_f32_16x16x32_f16(Al[1][s],Bh,acc1,0,0,0); \
    } \
    _Pragma("unroll") \
    for(int T=0;T<2;T++){ \
      v4f accT = T ? acc1 : acc0; \
      _Pragma("unroll") \
      for(int rr=0;rr<4;rr++){ \
        float q=fmaf(accT[rr],inv_w,off_w); \
        if(q>-2.0e9f && q<2.0e9f){ \
          int bin=(int)floorf(q); \
          int loc=base70[T][rr]+bin; \
          if((unsigned)loc<8960u){ \
            atomicAdd(&lh[loc>>1], 1u<<((loc&1)<<4)); \
          }else{ \
            int g=base+loc; \
            if(g>=0 && g<TOTBINS) atomicAdd(&hist[g],1u); \
          } \
        } \
      } \
    } }

  ISSUE(0);
  __syncthreads();
  for(int ii=0;ii<16;ii++){
    // even iter: compute buf0, prefetch buf1
    ISSUE(1);
    COMPUTE(0);
    __syncthreads();
    // odd iter: compute buf1, prefetch buf0 (except last)
    if(ii<15) ISSUE(0);
    COMPUTE(1);
    __syncthreads();
  }
#undef ISSUE
#undef COMPUTE
  for(int i=t;i<4480;i+=256){
    unsigned int c=lh[i];
    if(c&0xFFFFu) atomicAdd(&hist[base+2*i],   c&0xFFFFu);
    if(c>>16)     atomicAdd(&hist[base+2*i+1], c>>16);
  }
}

__global__ void k_argmax(const unsigned int* __restrict__ hist, float* __restrict__ out){
  int g = blockIdx.x*256 + threadIdx.x;
  const unsigned int* h = hist + (size_t)g*70;
  unsigned int best=h[0]; int arg=0;
  for(int k=1;k<70;k++){
    unsigned int c=h[k];
    if(c>best){ best=c; arg=k; }
  }
  out[g]=(float)arg;
}

extern "C" void kernel_launch(void* const* d_in, const int* in_sizes, int n_in,
                              void* d_out, int out_size, void* d_ws, size_t ws_size,
                              hipStream_t stream){
  const float* x  =(const float*)d_in[0];
  const float* w1 =(const float*)d_in[1];
  const float* b1 =(const float*)d_in[2];
  const float* g1 =(const float*)d_in[3];
  const float* be1=(const float*)d_in[4];
  const float* w2 =(const float*)d_in[5];
  const float* b2 =(const float*)d_in[6];
  const float* g2 =(const float*)d_in[7];
  const float* be2=(const float*)d_in[8];
  const float* w3 =(const float*)d_in[9];
  const float* b3 =(const float*)d_in[10];
  const float* g3 =(const float*)d_in[11];
  const float* be3=(const float*)d_in[12];

  float* ws=(float*)d_ws;
  unsigned int* hist=(unsigned int*)ws;
  float* partX = ws+OFF_PARTX;
  float* W1f   = ws+OFF_W1F;
  float* B1f   = ws+OFF_B1F;
  float* pMu1  = ws+OFF_PMU1;
  float* M1n   = ws+OFF_M1N;
  float* mu1   = ws+OFF_MU1;
  _Float16* w2h=(_Float16*)(ws+OFF_W2H);
  _Float16* w2l=(_Float16*)(ws+OFF_W2L);
  float* B2f   = ws+OFF_B2F;
  float* pMu2  = ws+OFF_PMU2;
  float* M2n   = ws+OFF_M2N;
  float* mu2   = ws+OFF_MU2;
  _Float16* w3h=(_Float16*)(ws+OFF_W3H);
  _Float16* w3l=(_Float16*)(ws+OFF_W3L);
  float* B3f   = ws+OFF_B3F;
  _Float16* h1h=(_Float16*)(ws+OFF_H1H);
  _Float16* h1l=(_Float16*)(ws+OFF_H1L);
  _Float16* h2h=(_Float16*)(ws+OFF_H2H);
  _Float16* h2l=(_Float16*)(ws+OFF_H2L);
  float* partM1=(float*)(ws+OFF_H2H);   // h2 region free until k_layer2
  float* partM2=(float*)(ws+OFF_H1H);   // h1 region free after k_layer2

  hipMemsetAsync(hist, 0, (size_t)TOTBINS*sizeof(unsigned int), stream);

  k_statsX  <<<256,256,0,stream>>>(x, partX);
  k_fold1   <<<1,  256,0,stream>>>(partX,w1,b1,g1,be1,W1f,B1f);
  k_layer1  <<<256,256,0,stream>>>(x,W1f,B1f,h1h,h1l);
  k_stats1  <<<256,256,0,stream>>>(h1h,h1l,partM1,pMu1);
  k_reduceM1<<<16, 256,0,stream>>>(partM1,pMu1,M1n,mu1);
  k_fold2   <<<128, 64,0,stream>>>(w2,b2,g2,be2,M1n,mu1,w2h,w2l,B2f);
  k_layer2  <<<2048,256,0,stream>>>(h1h,h1l,w2h,w2l,B2f,h2h,h2l);
  k_stats2  <<<256,256,0,stream>>>(h2h,h2l,partM2,pMu2);
  k_reduceM2<<<64, 256,0,stream>>>(partM2,pMu2,M2n,mu2);
  k_fold3   <<<1024,128,0,stream>>>(w3,b3,g3,be3,M2n,mu2,w3h,w3l,B3f);
  k_gemm3_hist<<<1024,256,0,stream>>>(h2h,h2l,w3h,w3l,B3f,hist);
  k_argmax  <<<64, 256,0,stream>>>(hist,(float*)d_out);
}